// Round 13
// baseline (25.796 us; speedup 1.0000x reference)
//
#include <hip/hip_runtime.h>
#include <stdint.h>

// qint embedding gather: out[t,:] = f32(w[x[t],:]) * scales[x[t]]  (FLOAT32 out)
//
// Round-13 correction: reference output dtype is float32 (not bf16).
// Rounds 2-12 all wrote byte-identical packed-bf16 into the f32 output
// buffer -> deterministic misread -> the bit-stable absmax 828. Writing
// f32 makes the kernel bit-exact vs the numpy reference (same f32 mul).
//
//   x:       [16384]        int32   token indices (= out_size/1024)
//   weights: [50257, 1024]  int32   (int8 values widened; in_npz=78.7MB)
//   scales:  [50257]        float32 per-row scales
//   out:     [16384, 1024]  float32
//
// One 256-thread block per token; thread t handles dims [4t, 4t+4):
//   dwordx4 int32 load -> 4x (cvt_f32_i32, mul) -> dwordx4 f32 store.
// Memory-bound: ~57 MB unique-row fetch + 67 MB write -> ~20 us @ 6.3 TB/s.

__global__ void qe_k(const int* __restrict__ x, const int* __restrict__ w,
                     const float* __restrict__ scales, float* __restrict__ out) {
    const int token = blockIdx.x, t = threadIdx.x;   // 256 threads/block

    // Block-uniform weight-layout sniff (free insurance): widened int8
    // satisfies v == sext(v & 0xFF) on all four probe words.
    const int4 p = *reinterpret_cast<const int4*>(w);
    const bool wide =
        (p.x == (int)(int8_t)p.x) && (p.y == (int)(int8_t)p.y) &&
        (p.z == (int)(int8_t)p.z) && (p.w == (int)(int8_t)p.w);

    const int idx = x[token];                        // block-uniform
    const float s = scales[idx];

    float4 o;
    if (wide) {
        // int32 table: row 4096 B; thread t loads 16 B (dwordx4), coalesced.
        const int4 v = reinterpret_cast<const int4*>(w + (size_t)idx * 1024)[t];
        o.x = (float)v.x * s;
        o.y = (float)v.y * s;
        o.z = (float)v.z * s;
        o.w = (float)v.w * s;
    } else {
        // packed int8 table: row 1024 B; thread t loads 4 B, coalesced.
        const int r = reinterpret_cast<const int*>(
            reinterpret_cast<const int8_t*>(w) + (size_t)idx * 1024)[t];
        o.x = (float)(int8_t)(r)       * s;
        o.y = (float)(int8_t)(r >> 8)  * s;
        o.z = (float)(int8_t)(r >> 16) * s;
        o.w = (float)(int8_t)(r >> 24) * s;
    }

    // out row = 4096 B; thread t stores 16 B (dwordx4), coalesced.
    reinterpret_cast<float4*>(out + (size_t)token * 1024)[t] = o;
}

extern "C" void kernel_launch(void* const* d_in, const int* in_sizes, int n_in,
                              void* d_out, int out_size, void* d_ws, size_t ws_size,
                              hipStream_t stream) {
    const int n_tokens = out_size / 1024;            // 16384
    if (n_tokens <= 0) return;

    // Bind inputs by element count (robust to ordering):
    // weights = largest; x = the one sized n_tokens; scales = remaining.
    int iw = 0;
    for (int i = 1; i < n_in; ++i)
        if (in_sizes[i] > in_sizes[iw]) iw = i;
    int ix = -1, is = -1;
    for (int i = 0; i < n_in; ++i) {
        if (i == iw) continue;
        if (in_sizes[i] == n_tokens && ix < 0) ix = i; else is = i;
    }
    if (ix < 0) ix = (iw == 0) ? 1 : 0;
    if (is < 0) is = 3 - ix - iw;

    qe_k<<<n_tokens, 256, 0, stream>>>((const int*)d_in[ix], (const int*)d_in[iw],
                                       (const float*)d_in[is], (float*)d_out);
}